// Round 7
// baseline (809.050 us; speedup 1.0000x reference)
//
#include <hip/hip_runtime.h>
#include <hip/hip_bf16.h>

// Geometry (fixed): B=1, C=8, D=H=W=128.
constexpr int HW2 = 16384;
constexpr int DHW = 2097152;

// MFMA staging: LDS cell = 8 ci (bf16, 16 B) at (g = dz*3+dy group, xi).
constexpr int PKG = 13;   // groups per xi row (9 used + 3 K-pad + 1 pitch pad)
constexpr int XT  = 130;  // staged x extent: x = -1 .. 128

typedef short bf16x8 __attribute__((ext_vector_type(8)));  // 8 bf16 = 4 VGPR
typedef float f32x4  __attribute__((ext_vector_type(4)));

__device__ inline unsigned short f2b(float f) {
  __hip_bfloat16 h = __float2bfloat16(f);
  return *(unsigned short*)&h;
}
__device__ inline float b2f(unsigned short u) {
  __hip_bfloat16 h = *(__hip_bfloat16*)&u;
  return __bfloat162float(h);
}

// ---------------------------------------------------------------------------
// Prep: pack w1/w2 into MFMA A-fragment order, bf16, dx-split (R6-proven).
// ---------------------------------------------------------------------------
__global__ __launch_bounds__(256) void k_prep(
    const float* __restrict__ w1, const float* __restrict__ w2,
    unsigned short* __restrict__ Wpack2, unsigned short* __restrict__ Wpack1) {
  int i = blockIdx.x * 256 + threadIdx.x;
  if (i < 9216) {
    int j = i & 7;
    int lane = (i >> 3) & 63;
    int Mt = (i >> 9) & 1;
    int g2 = i >> 10;         // dx*3 + s
    int s = g2 % 3, dx = g2 / 3;
    int oc = Mt * 16 + (lane & 15);
    int kr = s * 32 + (lane >> 4) * 8 + j;
    int ci = kr & 7, g = kr >> 3;
    float w = 0.f;
    if (oc < 27 && g < 9) {
      int dzr = g / 3, dyr = g % 3;
      w = w2[(oc * 8 + ci) * 27 + dzr * 9 + dyr * 3 + dx];
    }
    Wpack2[i] = f2b(w);
  }
  int jj = i - 9216;
  if (jj >= 0 && jj < 4608) {
    int j = jj & 7;
    int lane = (jj >> 3) & 63;
    int g2 = jj >> 9;         // dx*3 + s
    int s = g2 % 3, dx = g2 / 3;
    int oc = lane & 15;
    int kr = s * 32 + (lane >> 4) * 8 + j;
    int ci = kr & 7, g = kr >> 3;
    float w = 0.f;
    if (oc < 8 && g < 9) {
      int dzr = g / 3, dyr = g % 3;
      w = w1[(oc * 8 + ci) * 27 + dzr * 9 + dyr * 3 + dx];
    }
    Wpack1[jj] = f2b(w);
  }
}

// ---------------------------------------------------------------------------
// Transpose x: [ci][vox] fp32 -> xb [vox][ci] bf16 (conv1m staging input)
//                            -> xc [vox][ci] fp32 (adapt chain input)
// ---------------------------------------------------------------------------
__global__ __launch_bounds__(256) void k_xpose(
    const float* __restrict__ x, unsigned short* __restrict__ xb,
    float* __restrict__ xc) {
  int idx = blockIdx.x * 256 + threadIdx.x;  // voxel
  float f[8];
#pragma unroll
  for (int c = 0; c < 8; ++c) f[c] = x[(size_t)c * DHW + idx];
  unsigned v[4];
#pragma unroll
  for (int p = 0; p < 4; ++p)
    v[p] = (unsigned)f2b(f[2 * p]) | ((unsigned)f2b(f[2 * p + 1]) << 16);
  ((uint4*)xb)[idx] = make_uint4(v[0], v[1], v[2], v[3]);
  float4* o = (float4*)(xc + (size_t)idx * 8);
  o[0] = make_float4(f[0], f[1], f[2], f[3]);
  o[1] = make_float4(f[4], f[5], f[6], f[7]);
}

// ---------------------------------------------------------------------------
// Kernel 1: conv3d + bias + ReLU (8->8), implicit-GEMM MFMA (R6-proven).
// ---------------------------------------------------------------------------
__global__ __launch_bounds__(256) void k_conv1m(
    const unsigned short* __restrict__ xb,
    const unsigned short* __restrict__ Wpack1,
    const float* __restrict__ b1, unsigned short* __restrict__ hb) {
  __shared__ __align__(16) unsigned short T[XT * PKG * 8];
  const int tid  = threadIdx.x;
  const int lane = tid & 63;
  const int wv   = tid >> 6;
  const int z0 = blockIdx.x >> 7;
  const int y0 = blockIdx.x & 127;

  bf16x8 wf[3][3];
  {
    const bf16x8* wp = (const bf16x8*)Wpack1;
#pragma unroll
    for (int dx = 0; dx < 3; ++dx)
#pragma unroll
      for (int s = 0; s < 3; ++s)
        wf[dx][s] = wp[(dx * 3 + s) * 64 + lane];
  }

  const uint4* src = (const uint4*)xb;
  uint4* dst = (uint4*)T;
#pragma unroll 1
  for (int c = tid; c < 12 * XT; c += 256) {
    int g  = c / XT;
    int xi = c - g * XT;
    uint4 v = make_uint4(0u, 0u, 0u, 0u);
    if (g < 9) {
      int z = z0 + g / 3 - 1, y = y0 + g % 3 - 1, xg = xi - 1;
      if ((unsigned)z < 128u && (unsigned)y < 128u && (unsigned)xg < 128u)
        v = src[(z * 128 + y) * 128 + xg];
    }
    dst[xi * PKG + g] = v;
  }
  __syncthreads();

  f32x4 acc[2];
#pragma unroll
  for (int nt = 0; nt < 2; ++nt) acc[nt] = (f32x4){0.f, 0.f, 0.f, 0.f};

  const int n = lane & 15;
  const int q = lane >> 4;
  const int xbase = wv * 32 + n;

#pragma unroll
  for (int dx = 0; dx < 3; ++dx) {
#pragma unroll
    for (int s = 0; s < 3; ++s) {
      bf16x8 bfr[2];
#pragma unroll
      for (int nt = 0; nt < 2; ++nt) {
        int off = ((xbase + nt * 16 + dx) * PKG + (s * 4 + q)) * 8;
        bfr[nt] = *(const bf16x8*)&T[off];
      }
#pragma unroll
      for (int nt = 0; nt < 2; ++nt)
        acc[nt] = __builtin_amdgcn_mfma_f32_16x16x32_bf16(
            wf[dx][s], bfr[nt], acc[nt], 0, 0, 0);
    }
  }

  const int voxrow = (z0 * 128 + y0) * 128;
  if (q < 2) {
#pragma unroll
    for (int nt = 0; nt < 2; ++nt) {
      const int vox = voxrow + wv * 32 + nt * 16 + n;
      ushort4 o;
      o.x = f2b(fmaxf(acc[nt][0] + b1[q * 4 + 0], 0.f));
      o.y = f2b(fmaxf(acc[nt][1] + b1[q * 4 + 1], 0.f));
      o.z = f2b(fmaxf(acc[nt][2] + b1[q * 4 + 2], 0.f));
      o.w = f2b(fmaxf(acc[nt][3] + b1[q * 4 + 3], 0.f));
      *(ushort4*)(hb + (size_t)vox * 8 + q * 4) = o;
    }
  }
}

// ---------------------------------------------------------------------------
// Kernel 2: conv3d (8->27) + fused L1 norm, implicit-GEMM MFMA (R6-proven).
// ---------------------------------------------------------------------------
__global__ __launch_bounds__(256) void k_conv2(
    const unsigned short* __restrict__ hb,
    const unsigned short* __restrict__ Wpack2,
    unsigned short* __restrict__ wn) {
  __shared__ __align__(16) unsigned short T[XT * PKG * 8];
  const int tid  = threadIdx.x;
  const int lane = tid & 63;
  const int wv   = tid >> 6;
  const int z0 = blockIdx.x >> 7;
  const int y0 = blockIdx.x & 127;

  bf16x8 wf[3][3][2];
  {
    const bf16x8* wp = (const bf16x8*)Wpack2;
#pragma unroll
    for (int dx = 0; dx < 3; ++dx)
#pragma unroll
      for (int s = 0; s < 3; ++s)
#pragma unroll
        for (int mt = 0; mt < 2; ++mt)
          wf[dx][s][mt] = wp[((dx * 3 + s) * 2 + mt) * 64 + lane];
  }

  const uint4* src = (const uint4*)hb;
  uint4* dst = (uint4*)T;
#pragma unroll 1
  for (int c = tid; c < 12 * XT; c += 256) {
    int g  = c / XT;
    int xi = c - g * XT;
    uint4 v = make_uint4(0u, 0u, 0u, 0u);
    if (g < 9) {
      int z = z0 + g / 3 - 1, y = y0 + g % 3 - 1, xg = xi - 1;
      if ((unsigned)z < 128u && (unsigned)y < 128u && (unsigned)xg < 128u)
        v = src[(z * 128 + y) * 128 + xg];
    }
    dst[xi * PKG + g] = v;
  }
  __syncthreads();

  f32x4 acc[2][2];  // [nt][mt]
#pragma unroll
  for (int nt = 0; nt < 2; ++nt)
#pragma unroll
    for (int mt = 0; mt < 2; ++mt) acc[nt][mt] = (f32x4){0.f, 0.f, 0.f, 0.f};

  const int n = lane & 15;
  const int q = lane >> 4;
  const int xbase = wv * 32 + n;

#pragma unroll
  for (int dx = 0; dx < 3; ++dx) {
#pragma unroll
    for (int s = 0; s < 3; ++s) {
      bf16x8 bfr[2];
#pragma unroll
      for (int nt = 0; nt < 2; ++nt) {
        int off = ((xbase + nt * 16 + dx) * PKG + (s * 4 + q)) * 8;
        bfr[nt] = *(const bf16x8*)&T[off];
      }
#pragma unroll
      for (int mt = 0; mt < 2; ++mt)
#pragma unroll
        for (int nt = 0; nt < 2; ++nt)
          acc[nt][mt] = __builtin_amdgcn_mfma_f32_16x16x32_bf16(
              wf[dx][s][mt], bfr[nt], acc[nt][mt], 0, 0, 0);
    }
  }

  const int voxrow = (z0 * 128 + y0) * 128;
#pragma unroll
  for (int nt = 0; nt < 2; ++nt) {
    float ns = 0.f;
#pragma unroll
    for (int r = 0; r < 4; ++r) ns += fabsf(acc[nt][0][r]);
#pragma unroll
    for (int r = 0; r < 4; ++r) {
      int oc = 16 + q * 4 + r;
      ns += (oc < 27) ? fabsf(acc[nt][1][r]) : 0.f;
    }
    ns += __shfl_xor(ns, 16);
    ns += __shfl_xor(ns, 32);
    float sc = 1.f / fmaxf(ns, 1e-12f);
    const int vox = voxrow + wv * 32 + nt * 16 + n;
#pragma unroll
    for (int r = 0; r < 4; ++r) {
      int oc = q * 4 + r;
      wn[(size_t)oc * DHW + vox] = f2b(acc[nt][0][r] * sc);
    }
#pragma unroll
    for (int r = 0; r < 4; ++r) {
      int oc = 16 + q * 4 + r;
      if (oc < 27)
        wn[(size_t)oc * DHW + vox] = f2b(acc[nt][1][r] * sc);
    }
  }
}

// ---------------------------------------------------------------------------
// Kernel 3: adaptive 3x3x3 conv, channels-last fp32 in, 4 voxels/thread.
// Per (dz,dy) group: 3 ushort4 wt loads + 12 contiguous float4 window loads
// (6 voxels x 32 B), branchless (row clamp + wt zeroing). std_out selects
// output layout: 0 = channels-last (intermediate), 1 = [c][vox] (final).
// ---------------------------------------------------------------------------
__global__ __launch_bounds__(256) void k_adapt(
    const float* __restrict__ in, const unsigned short* __restrict__ wn,
    float* __restrict__ out, int std_out) {
  const int t = blockIdx.x * 256 + threadIdx.x;  // [0, DHW/4)
  const int x0 = (t & 31) * 4;
  const int rest = t >> 5;
  const int y = rest & 127;
  const int z = rest >> 7;
  const int vox0 = (z * 128 + y) * 128 + x0;

  // clamped x-window offsets (in floats, cl layout: voxel*8)
  int xoff[6];
#pragma unroll
  for (int k = 0; k < 6; ++k) {
    int xx = x0 - 1 + k;
    int xc = min(max(xx, 0), 127);
    xoff[k] = xc * 8;
  }
  const bool xlo_ok = (x0 > 0);
  const bool xhi_ok = (x0 < 124);

  float acc[8][4];
#pragma unroll
  for (int c = 0; c < 8; ++c)
#pragma unroll
    for (int v = 0; v < 4; ++v) acc[c][v] = 0.f;

#pragma unroll 1
  for (int g = 0; g < 9; ++g) {
    const int dz = g / 3 - 1, dy = g % 3 - 1;
    const int zz = z + dz, yy = y + dy;
    const bool okg = ((unsigned)zz < 128u) & ((unsigned)yy < 128u);
    const int zc = okg ? zz : z;
    const int yc = okg ? yy : y;
    const float* rowb = in + (size_t)(zc * 128 + yc) * 1024;

    // per-tap weights (zeroed when group/edge invalid)
    float wtf[3][4];
#pragma unroll
    for (int dxi = 0; dxi < 3; ++dxi) {
      ushort4 wv = *(const ushort4*)(wn + (size_t)(g * 3 + dxi) * DHW + vox0);
      wtf[dxi][0] = okg ? b2f(wv.x) : 0.f;
      wtf[dxi][1] = okg ? b2f(wv.y) : 0.f;
      wtf[dxi][2] = okg ? b2f(wv.z) : 0.f;
      wtf[dxi][3] = okg ? b2f(wv.w) : 0.f;
    }
    wtf[0][0] = xlo_ok ? wtf[0][0] : 0.f;  // window k=0 invalid at x0==0
    wtf[2][3] = xhi_ok ? wtf[2][3] : 0.f;  // window k=5 invalid at x0==124

    // 6-voxel window, 8 ch each: 12 independent float4 loads
    float win[6][8];
#pragma unroll
    for (int k = 0; k < 6; ++k) {
      float4 lo = *(const float4*)(rowb + xoff[k]);
      float4 hi = *(const float4*)(rowb + xoff[k] + 4);
      win[k][0] = lo.x; win[k][1] = lo.y; win[k][2] = lo.z; win[k][3] = lo.w;
      win[k][4] = hi.x; win[k][5] = hi.y; win[k][6] = hi.z; win[k][7] = hi.w;
    }

#pragma unroll
    for (int dxi = 0; dxi < 3; ++dxi)
#pragma unroll
      for (int v = 0; v < 4; ++v) {
        float w = wtf[dxi][v];
#pragma unroll
        for (int c = 0; c < 8; ++c)
          acc[c][v] = fmaf(win[v + dxi][c], w, acc[c][v]);
      }
  }

  if (std_out) {
#pragma unroll
    for (int c = 0; c < 8; ++c)
      *(float4*)(out + (size_t)c * DHW + vox0) =
          make_float4(acc[c][0], acc[c][1], acc[c][2], acc[c][3]);
  } else {
    float* ob = out + (size_t)vox0 * 8;
#pragma unroll
    for (int v = 0; v < 4; ++v) {
      *(float4*)(ob + v * 8) =
          make_float4(acc[0][v], acc[1][v], acc[2][v], acc[3][v]);
      *(float4*)(ob + v * 8 + 4) =
          make_float4(acc[4][v], acc[5][v], acc[6][v], acc[7][v]);
    }
  }
}

// ---------------------------------------------------------------------------
extern "C" void kernel_launch(void* const* d_in, const int* in_sizes, int n_in,
                              void* d_out, int out_size, void* d_ws, size_t ws_size,
                              hipStream_t stream) {
  const float* x  = (const float*)d_in[0];
  const float* w1 = (const float*)d_in[1];
  const float* b1 = (const float*)d_in[2];
  const float* w2 = (const float*)d_in[3];
  float* out = (float*)d_out;

  // Workspace (236 MB, same footprint as R3-R6):
  //   [0]    xb  bf16 cl  32 MiB   (dead after conv1m)
  //   [32M]  hb  bf16 cl  32 MiB   (dead after conv2)
  //   [64M]  wn  bf16     108 MiB  (live through all adapt passes)
  //   [172M] xc  fp32 cl  64 MiB
  //   [236M] Wpack2 | Wpack1
  // t1 (fp32 cl, 64 MiB) overlays xb+hb once both are dead.
  char* ws = (char*)d_ws;
  unsigned short* xb = (unsigned short*)ws;
  unsigned short* hb = (unsigned short*)(ws + (size_t)8 * DHW * 2);
  unsigned short* wn = (unsigned short*)(ws + (size_t)16 * DHW * 2);
  float* xc = (float*)(ws + (size_t)16 * DHW * 2 + (size_t)27 * DHW * 2);
  float* t1 = (float*)ws;
  unsigned short* Wpack2 =
      (unsigned short*)(ws + (size_t)16 * DHW * 2 + (size_t)27 * DHW * 2 +
                        (size_t)8 * DHW * 4);
  unsigned short* Wpack1 = Wpack2 + 9216;

  dim3 blk(256);
  k_prep<<<54, blk, 0, stream>>>(w1, w2, Wpack2, Wpack1);
  k_xpose<<<DHW / 256, blk, 0, stream>>>(x, xb, xc);
  k_conv1m<<<128 * 128, blk, 0, stream>>>(xb, Wpack1, b1, hb);
  k_conv2<<<128 * 128, blk, 0, stream>>>(hb, Wpack2, wn);
  // adaptive chain (channels-last): xc -> t1 -> xc -> d_out(std layout)
  k_adapt<<<DHW / 4 / 256, blk, 0, stream>>>(xc, wn, t1, 0);
  k_adapt<<<DHW / 4 / 256, blk, 0, stream>>>(t1, wn, xc, 0);
  k_adapt<<<DHW / 4 / 256, blk, 0, stream>>>(xc, wn, out, 1);
}

// Round 8
// 722.253 us; speedup vs baseline: 1.1202x; 1.1202x over previous
//
#include <hip/hip_runtime.h>
#include <hip/hip_bf16.h>

// Geometry (fixed): B=1, C=8, D=H=W=128.
constexpr int HW2 = 16384;
constexpr int DHW = 2097152;

// MFMA staging: LDS cell = 8 ci (bf16, 16 B) at (g = dz*3+dy group, xi).
constexpr int PKG = 13;   // groups per xi row (9 used + 3 K-pad + 1 pitch pad)
constexpr int XT  = 130;  // staged x extent: x = -1 .. 128

typedef short bf16x8 __attribute__((ext_vector_type(8)));  // 8 bf16 = 4 VGPR
typedef float f32x4  __attribute__((ext_vector_type(4)));

__device__ inline unsigned short f2b(float f) {
  __hip_bfloat16 h = __float2bfloat16(f);
  return *(unsigned short*)&h;
}
__device__ inline float blo(unsigned u) {   // low bf16 of a packed pair
  unsigned v = u << 16;
  return __builtin_bit_cast(float, v);
}
__device__ inline float bhi(unsigned u) {   // high bf16 of a packed pair
  unsigned v = u & 0xFFFF0000u;
  return __builtin_bit_cast(float, v);
}

// ---------------------------------------------------------------------------
// Prep: pack w1/w2 into MFMA A-fragment order, bf16, dx-split (R6-proven).
// ---------------------------------------------------------------------------
__global__ __launch_bounds__(256) void k_prep(
    const float* __restrict__ w1, const float* __restrict__ w2,
    unsigned short* __restrict__ Wpack2, unsigned short* __restrict__ Wpack1) {
  int i = blockIdx.x * 256 + threadIdx.x;
  if (i < 9216) {
    int j = i & 7;
    int lane = (i >> 3) & 63;
    int Mt = (i >> 9) & 1;
    int g2 = i >> 10;         // dx*3 + s
    int s = g2 % 3, dx = g2 / 3;
    int oc = Mt * 16 + (lane & 15);
    int kr = s * 32 + (lane >> 4) * 8 + j;
    int ci = kr & 7, g = kr >> 3;
    float w = 0.f;
    if (oc < 27 && g < 9) {
      int dzr = g / 3, dyr = g % 3;
      w = w2[(oc * 8 + ci) * 27 + dzr * 9 + dyr * 3 + dx];
    }
    Wpack2[i] = f2b(w);
  }
  int jj = i - 9216;
  if (jj >= 0 && jj < 4608) {
    int j = jj & 7;
    int lane = (jj >> 3) & 63;
    int g2 = jj >> 9;         // dx*3 + s
    int s = g2 % 3, dx = g2 / 3;
    int oc = lane & 15;
    int kr = s * 32 + (lane >> 4) * 8 + j;
    int ci = kr & 7, g = kr >> 3;
    float w = 0.f;
    if (oc < 8 && g < 9) {
      int dzr = g / 3, dyr = g % 3;
      w = w1[(oc * 8 + ci) * 27 + dzr * 9 + dyr * 3 + dx];
    }
    Wpack1[jj] = f2b(w);
  }
}

// ---------------------------------------------------------------------------
// Transpose x: [ci][vox] fp32 -> xb [vox][ci] bf16 (conv1m staging input)
// ---------------------------------------------------------------------------
__global__ __launch_bounds__(256) void k_xpose(
    const float* __restrict__ x, unsigned short* __restrict__ xb) {
  int idx = blockIdx.x * 256 + threadIdx.x;  // voxel
  float f[8];
#pragma unroll
  for (int c = 0; c < 8; ++c) f[c] = x[(size_t)c * DHW + idx];
  unsigned v[4];
#pragma unroll
  for (int p = 0; p < 4; ++p)
    v[p] = (unsigned)f2b(f[2 * p]) | ((unsigned)f2b(f[2 * p + 1]) << 16);
  ((uint4*)xb)[idx] = make_uint4(v[0], v[1], v[2], v[3]);
}

// ---------------------------------------------------------------------------
// Kernel 1: conv3d + bias + ReLU (8->8), implicit-GEMM MFMA (R6-proven).
// ---------------------------------------------------------------------------
__global__ __launch_bounds__(256) void k_conv1m(
    const unsigned short* __restrict__ xb,
    const unsigned short* __restrict__ Wpack1,
    const float* __restrict__ b1, unsigned short* __restrict__ hb) {
  __shared__ __align__(16) unsigned short T[XT * PKG * 8];
  const int tid  = threadIdx.x;
  const int lane = tid & 63;
  const int wv   = tid >> 6;
  const int z0 = blockIdx.x >> 7;
  const int y0 = blockIdx.x & 127;

  bf16x8 wf[3][3];
  {
    const bf16x8* wp = (const bf16x8*)Wpack1;
#pragma unroll
    for (int dx = 0; dx < 3; ++dx)
#pragma unroll
      for (int s = 0; s < 3; ++s)
        wf[dx][s] = wp[(dx * 3 + s) * 64 + lane];
  }

  const uint4* src = (const uint4*)xb;
  uint4* dst = (uint4*)T;
#pragma unroll 1
  for (int c = tid; c < 12 * XT; c += 256) {
    int g  = c / XT;
    int xi = c - g * XT;
    uint4 v = make_uint4(0u, 0u, 0u, 0u);
    if (g < 9) {
      int z = z0 + g / 3 - 1, y = y0 + g % 3 - 1, xg = xi - 1;
      if ((unsigned)z < 128u && (unsigned)y < 128u && (unsigned)xg < 128u)
        v = src[(z * 128 + y) * 128 + xg];
    }
    dst[xi * PKG + g] = v;
  }
  __syncthreads();

  f32x4 acc[2];
#pragma unroll
  for (int nt = 0; nt < 2; ++nt) acc[nt] = (f32x4){0.f, 0.f, 0.f, 0.f};

  const int n = lane & 15;
  const int q = lane >> 4;
  const int xbase = wv * 32 + n;

#pragma unroll
  for (int dx = 0; dx < 3; ++dx) {
#pragma unroll
    for (int s = 0; s < 3; ++s) {
      bf16x8 bfr[2];
#pragma unroll
      for (int nt = 0; nt < 2; ++nt) {
        int off = ((xbase + nt * 16 + dx) * PKG + (s * 4 + q)) * 8;
        bfr[nt] = *(const bf16x8*)&T[off];
      }
#pragma unroll
      for (int nt = 0; nt < 2; ++nt)
        acc[nt] = __builtin_amdgcn_mfma_f32_16x16x32_bf16(
            wf[dx][s], bfr[nt], acc[nt], 0, 0, 0);
    }
  }

  const int voxrow = (z0 * 128 + y0) * 128;
  if (q < 2) {
#pragma unroll
    for (int nt = 0; nt < 2; ++nt) {
      const int vox = voxrow + wv * 32 + nt * 16 + n;
      ushort4 o;
      o.x = f2b(fmaxf(acc[nt][0] + b1[q * 4 + 0], 0.f));
      o.y = f2b(fmaxf(acc[nt][1] + b1[q * 4 + 1], 0.f));
      o.z = f2b(fmaxf(acc[nt][2] + b1[q * 4 + 2], 0.f));
      o.w = f2b(fmaxf(acc[nt][3] + b1[q * 4 + 3], 0.f));
      *(ushort4*)(hb + (size_t)vox * 8 + q * 4) = o;
    }
  }
}

// ---------------------------------------------------------------------------
// Kernel 2: conv3d (8->27) + fused L1 norm, implicit-GEMM MFMA (R6-proven).
// ---------------------------------------------------------------------------
__global__ __launch_bounds__(256) void k_conv2(
    const unsigned short* __restrict__ hb,
    const unsigned short* __restrict__ Wpack2,
    unsigned short* __restrict__ wn) {
  __shared__ __align__(16) unsigned short T[XT * PKG * 8];
  const int tid  = threadIdx.x;
  const int lane = tid & 63;
  const int wv   = tid >> 6;
  const int z0 = blockIdx.x >> 7;
  const int y0 = blockIdx.x & 127;

  bf16x8 wf[3][3][2];
  {
    const bf16x8* wp = (const bf16x8*)Wpack2;
#pragma unroll
    for (int dx = 0; dx < 3; ++dx)
#pragma unroll
      for (int s = 0; s < 3; ++s)
#pragma unroll
        for (int mt = 0; mt < 2; ++mt)
          wf[dx][s][mt] = wp[((dx * 3 + s) * 2 + mt) * 64 + lane];
  }

  const uint4* src = (const uint4*)hb;
  uint4* dst = (uint4*)T;
#pragma unroll 1
  for (int c = tid; c < 12 * XT; c += 256) {
    int g  = c / XT;
    int xi = c - g * XT;
    uint4 v = make_uint4(0u, 0u, 0u, 0u);
    if (g < 9) {
      int z = z0 + g / 3 - 1, y = y0 + g % 3 - 1, xg = xi - 1;
      if ((unsigned)z < 128u && (unsigned)y < 128u && (unsigned)xg < 128u)
        v = src[(z * 128 + y) * 128 + xg];
    }
    dst[xi * PKG + g] = v;
  }
  __syncthreads();

  f32x4 acc[2][2];  // [nt][mt]
#pragma unroll
  for (int nt = 0; nt < 2; ++nt)
#pragma unroll
    for (int mt = 0; mt < 2; ++mt) acc[nt][mt] = (f32x4){0.f, 0.f, 0.f, 0.f};

  const int n = lane & 15;
  const int q = lane >> 4;
  const int xbase = wv * 32 + n;

#pragma unroll
  for (int dx = 0; dx < 3; ++dx) {
#pragma unroll
    for (int s = 0; s < 3; ++s) {
      bf16x8 bfr[2];
#pragma unroll
      for (int nt = 0; nt < 2; ++nt) {
        int off = ((xbase + nt * 16 + dx) * PKG + (s * 4 + q)) * 8;
        bfr[nt] = *(const bf16x8*)&T[off];
      }
#pragma unroll
      for (int mt = 0; mt < 2; ++mt)
#pragma unroll
        for (int nt = 0; nt < 2; ++nt)
          acc[nt][mt] = __builtin_amdgcn_mfma_f32_16x16x32_bf16(
              wf[dx][s][mt], bfr[nt], acc[nt][mt], 0, 0, 0);
    }
  }

  const int voxrow = (z0 * 128 + y0) * 128;
#pragma unroll
  for (int nt = 0; nt < 2; ++nt) {
    float ns = 0.f;
#pragma unroll
    for (int r = 0; r < 4; ++r) ns += fabsf(acc[nt][0][r]);
#pragma unroll
    for (int r = 0; r < 4; ++r) {
      int oc = 16 + q * 4 + r;
      ns += (oc < 27) ? fabsf(acc[nt][1][r]) : 0.f;
    }
    ns += __shfl_xor(ns, 16);
    ns += __shfl_xor(ns, 32);
    float sc = 1.f / fmaxf(ns, 1e-12f);
    const int vox = voxrow + wv * 32 + nt * 16 + n;
#pragma unroll
    for (int r = 0; r < 4; ++r) {
      int oc = q * 4 + r;
      wn[(size_t)oc * DHW + vox] = f2b(acc[nt][0][r] * sc);
    }
#pragma unroll
    for (int r = 0; r < 4; ++r) {
      int oc = 16 + q * 4 + r;
      if (oc < 27)
        wn[(size_t)oc * DHW + vox] = f2b(acc[nt][1][r] * sc);
    }
  }
}

// ---------------------------------------------------------------------------
// Kernel 3: adaptive 3x3x3 conv. R6-proven layout ([c][vox] fp32 in/out,
// 4 voxels/thread) + three fixes for the latency bound:
//   1. all 27 wt loads hoisted (packed uint2, decoded at use)
//   2. branchless groups (clamped row + weight zeroing)
//   3. XCD z-slab swizzle (XCD = blockIdx%8 assumption; perf-only)
// ---------------------------------------------------------------------------
__global__ __launch_bounds__(256) void k_adapt(
    const float* __restrict__ in, const unsigned short* __restrict__ wn,
    float* __restrict__ out) {
  // Swizzle: each XCD owns z in [16*xcd, 16*xcd+16); y-groups sweep inner.
  const int b = blockIdx.x;           // [0, 2048)
  const int xcd = b & 7;
  const int i = b >> 3;               // [0, 256)
  const int z = xcd * 16 + (i >> 4);
  const int yg = i & 15;

  const int t = threadIdx.x;
  const int x0 = (t & 31) * 4;
  const int y = yg * 8 + (t >> 5);
  const int vox0 = (z * 128 + y) * 128 + x0;

  // 1) hoist all 27 per-voxel weight loads (27 x 8 B, independent)
  uint2 wtp[27];
#pragma unroll
  for (int tap = 0; tap < 27; ++tap)
    wtp[tap] = *(const uint2*)(wn + (size_t)tap * DHW + vox0);

  const bool xlo_ok = (x0 > 0);
  const bool xhi_ok = (x0 < 124);
  const int xm1 = xlo_ok ? x0 - 1 : 0;
  const int xp4 = xhi_ok ? x0 + 4 : 127;

  float acc[8][4];
#pragma unroll
  for (int c = 0; c < 8; ++c)
#pragma unroll
    for (int v = 0; v < 4; ++v) acc[c][v] = 0.f;

#pragma unroll 3
  for (int g = 0; g < 9; ++g) {
    const int dz = g / 3 - 1, dy = g % 3 - 1;
    const int zz = z + dz, yy = y + dy;
    const bool okg = ((unsigned)zz < 128u) & ((unsigned)yy < 128u);
    const int rowb = ((okg ? zz : z) * 128 + (okg ? yy : y)) * 128;

    // decode weights; zero invalid group / x-edge taps
    float wtf[3][4];
#pragma unroll
    for (int dxi = 0; dxi < 3; ++dxi) {
      uint2 wv = wtp[g * 3 + dxi];
      wtf[dxi][0] = okg ? blo(wv.x) : 0.f;
      wtf[dxi][1] = okg ? bhi(wv.x) : 0.f;
      wtf[dxi][2] = okg ? blo(wv.y) : 0.f;
      wtf[dxi][3] = okg ? bhi(wv.y) : 0.f;
    }
    if (!xlo_ok) wtf[0][0] = 0.f;     // window k=0 invalid at x0==0
    if (!xhi_ok) wtf[2][3] = 0.f;     // window k=5 invalid at x0==124

#pragma unroll
    for (int c = 0; c < 8; ++c) {
      const float* row = in + (size_t)c * DHW + rowb;
      float4 mid = *(const float4*)(row + x0);
      float s_[6];
      s_[0] = row[xm1];
      s_[1] = mid.x; s_[2] = mid.y; s_[3] = mid.z; s_[4] = mid.w;
      s_[5] = row[xp4];
#pragma unroll
      for (int dxi = 0; dxi < 3; ++dxi)
#pragma unroll
        for (int v = 0; v < 4; ++v)
          acc[c][v] = fmaf(s_[v + dxi], wtf[dxi][v], acc[c][v]);
    }
  }

#pragma unroll
  for (int c = 0; c < 8; ++c)
    *(float4*)(out + (size_t)c * DHW + vox0) =
        make_float4(acc[c][0], acc[c][1], acc[c][2], acc[c][3]);
}

// ---------------------------------------------------------------------------
extern "C" void kernel_launch(void* const* d_in, const int* in_sizes, int n_in,
                              void* d_out, int out_size, void* d_ws, size_t ws_size,
                              hipStream_t stream) {
  const float* x  = (const float*)d_in[0];
  const float* w1 = (const float*)d_in[1];
  const float* b1 = (const float*)d_in[2];
  const float* w2 = (const float*)d_in[3];
  float* out = (float*)d_out;

  // Workspace (R6 scheme): xb bf16 32MiB | hb bf16 32MiB | wn bf16 108MiB |
  //                        tb fp32 64MiB | Wpack2 | Wpack1
  char* ws = (char*)d_ws;
  unsigned short* xb = (unsigned short*)ws;
  unsigned short* hb = (unsigned short*)(ws + (size_t)8 * DHW * 2);
  unsigned short* wn = (unsigned short*)(ws + (size_t)16 * DHW * 2);
  float* tb = (float*)(ws + (size_t)16 * DHW * 2 + (size_t)27 * DHW * 2);
  unsigned short* Wpack2 =
      (unsigned short*)(ws + (size_t)16 * DHW * 2 + (size_t)27 * DHW * 2 +
                        (size_t)8 * DHW * 4);
  unsigned short* Wpack1 = Wpack2 + 9216;

  dim3 blk(256);
  k_prep<<<54, blk, 0, stream>>>(w1, w2, Wpack2, Wpack1);
  k_xpose<<<DHW / 256, blk, 0, stream>>>(x, xb);
  k_conv1m<<<128 * 128, blk, 0, stream>>>(xb, Wpack1, b1, hb);
  k_conv2<<<128 * 128, blk, 0, stream>>>(hb, Wpack2, wn);
  // adaptive ping-pong: x -> out -> tb -> out
  k_adapt<<<DHW / 4 / 256, blk, 0, stream>>>(x, wn, out);
  k_adapt<<<DHW / 4 / 256, blk, 0, stream>>>(out, wn, tb);
  k_adapt<<<DHW / 4 / 256, blk, 0, stream>>>(tb, wn, out);
}